// Round 3
// baseline (29678.372 us; speedup 1.0000x reference)
//
#include <hip/hip_runtime.h>

#define B_   64
#define T_   512
#define KIN  512
#define NH   512
#define KEFF 3072   // 6 segments x 512
#define NBLK 64
#define NTHR 256

typedef __attribute__((ext_vector_type(8))) short short8;
typedef __attribute__((ext_vector_type(4))) float f32x4;

// bf16 round-to-nearest-even via bit ops
__device__ __forceinline__ unsigned short f2b(float f) {
    union { float f; unsigned int u; } v; v.f = f;
    unsigned int u = v.u;
    return (unsigned short)((u + 0x7FFFu + ((u >> 16) & 1u)) >> 16);
}
__device__ __forceinline__ float b2f(unsigned short h) {
    union { float f; unsigned int u; } v; v.u = ((unsigned int)h) << 16;
    return v.f;
}

// ---------------------------------------------------------------------------
// Prepack (unchanged, proven): B' [n][keff] bf16. Segments:
//   seg0: Whi(H) seg1: Whi(H) seg2: Wlo(H) seg3: Whi(X) seg4: Whi(X) seg5: Wlo(X)
// ---------------------------------------------------------------------------
__global__ void prepack(const float* __restrict__ Wxz, const float* __restrict__ Whz,
                        const float* __restrict__ Wxr, const float* __restrict__ Whr,
                        const float* __restrict__ Wxh, const float* __restrict__ Whh,
                        unsigned short* __restrict__ Bzr, unsigned short* __restrict__ Bh) {
    int keff = blockIdx.x * 256 + threadIdx.x;  // 0..3071
    int n    = blockIdx.y;                      // 0..1535
    int seg  = keff >> 9;
    int k    = keff & 511;
    const float* src;
    int c;
    if (n < 512)       { c = n;        src = (seg < 3) ? Whz : Wxz; }
    else if (n < 1024) { c = n - 512;  src = (seg < 3) ? Whr : Wxr; }
    else               { c = n - 1024; src = (seg < 3) ? Whh : Wxh; }
    float w = src[k * NH + c];
    unsigned short hi = f2b(w);
    unsigned short o  = (seg == 2 || seg == 5) ? f2b(w - b2f(hi)) : hi;
    if (n < 1024) Bzr[(size_t)n * KEFF + keff] = o;
    else          Bh[(size_t)(n - 1024) * KEFF + keff] = o;
}

// ---------------------------------------------------------------------------
// Coherent cross-block data: RELAXED + AGENT atomics. The compiler emits
// sc0/sc1 cache-bypassing ops AND tracks their vmcnt correctly (the round-2
// hand-asm version consumed load registers before data arrived -> NaN).
// No acquire/release anywhere -> zero buffer_inv / buffer_wbl2 in the binary
// -> plain-cached weights stay L2-warm for all 512 steps.
// ---------------------------------------------------------------------------
__device__ __forceinline__ unsigned int ald32(const unsigned int* p) {
    return __hip_atomic_load(p, __ATOMIC_RELAXED, __HIP_MEMORY_SCOPE_AGENT);
}
__device__ __forceinline__ float aldf(const float* p) {
    return __hip_atomic_load(p, __ATOMIC_RELAXED, __HIP_MEMORY_SCOPE_AGENT);
}
__device__ __forceinline__ unsigned long long ald64(const unsigned int* p) {
    return __hip_atomic_load((const unsigned long long*)p, __ATOMIC_RELAXED,
                             __HIP_MEMORY_SCOPE_AGENT);
}
__device__ __forceinline__ void ast32(unsigned int* p, unsigned int v) {
    __hip_atomic_store(p, v, __ATOMIC_RELAXED, __HIP_MEMORY_SCOPE_AGENT);
}
__device__ __forceinline__ void astf(float* p, float v) {
    __hip_atomic_store(p, v, __ATOMIC_RELAXED, __HIP_MEMORY_SCOPE_AGENT);
}

// fp32 -> bf16 hi/lo split of 8 consecutive X elements
__device__ __forceinline__ void cvt_x8(const float* xr, int kp, short8* ahi, short8* alo) {
    f32x4 x0 = *(const f32x4*)(xr + kp);
    f32x4 x1 = *(const f32x4*)(xr + kp + 4);
#pragma unroll
    for (int i = 0; i < 4; ++i) {
        unsigned short h0 = f2b(x0[i]);
        (*ahi)[i] = (short)h0; (*alo)[i] = (short)f2b(x0[i] - b2f(h0));
        unsigned short h1 = f2b(x1[i]);
        (*ahi)[4 + i] = (short)h1; (*alo)[4 + i] = (short)f2b(x1[i] - b2f(h1));
    }
}

// unpack 4 u64 of packed (hi | lo<<16) words into hi/lo short8 fragments
__device__ __forceinline__ void unpack8(const unsigned long long* q, short8* ahi, short8* alo) {
    union { unsigned int u[4]; short8 v; } H, L;
#pragma unroll
    for (int i = 0; i < 4; ++i) {
        unsigned int wa = (unsigned int)q[i];
        unsigned int wb = (unsigned int)(q[i] >> 32);
        H.u[i] = __builtin_amdgcn_perm(wb, wa, 0x05040100u);  // (hi0, hi1)
        L.u[i] = __builtin_amdgcn_perm(wb, wa, 0x07060302u);  // (lo0, lo1)
    }
    *ahi = H.v; *alo = L.v;
}

#define MFMA(a, b, c) __builtin_amdgcn_mfma_f32_16x16x32_bf16((a), (b), (c), 0, 0, 0)

// ---------------------------------------------------------------------------
// Persistent GRU. 64 blocks x 256 threads, 1 block/CU, full VGPR budget.
// Per step:
//  P1: X-GEMM (no dep, hides barrier skew) | tid0 spins B2(t-1) | sync |
//      H-GEMM (coherent packed-H loads, all 64 issued up-front) | sigmoid ->
//      Zbuf (z-blocks) / RH packed (r-blocks) | sync (drains stores) | arrive
//  P2: khalf1: X-GEMM -> comb(LDS); tid0 spins B1 | sync | khalf0: RH-GEMM +
//      epilogue (tanh, blend, H update packed) | sync | arrive
// ---------------------------------------------------------------------------
__global__ void __launch_bounds__(NTHR, 1) gru_seq(
    const float* __restrict__ X, const float* __restrict__ bz,
    const float* __restrict__ br, const float* __restrict__ bh,
    float* __restrict__ out, float* __restrict__ Zbuf,
    unsigned int* __restrict__ HP, unsigned int* __restrict__ RHP,
    const unsigned short* __restrict__ Bzr, const unsigned short* __restrict__ Bh,
    unsigned int* cnt) {
    const int blk  = blockIdx.x;
    const int tid  = threadIdx.x;
    const int wv   = tid >> 6;
    const int lane = tid & 63;
    const int fm   = lane & 15;      // A-row / B-col / C-col within 16
    const int fkc  = lane >> 4;      // k-chunk 0..3
    const int fk   = fkc * 8;

    __shared__ float comb[2][256];

    // phase-1 geometry: block owns zr-ntile blk (16 cols), wave owns mtile wv
    const int m1 = wv * 16 + fm;
    const unsigned short* Bp1 = Bzr + (size_t)(blk * 16 + fm) * KEFF;
    const int c1 = blk * 16 + fm;    // zr col 0..1023 (block-uniform z vs r)

    // phase-2 geometry: 128 output tiles, 2 per block; K split across wave pairs
    const int task  = blk * 2 + (wv >> 1);
    const int mt2   = task & 3;
    const int nt2   = task >> 2;
    const int khalf = wv & 1;        // 0: RH half (post-B1), 1: X half (no dep)
    const int slot  = wv >> 1;
    const int m2    = mt2 * 16 + fm;
    const unsigned short* Bp2 = Bh + (size_t)(nt2 * 16 + fm) * KEFF;
    const int c2 = nt2 * 16 + fm;

    for (int t = 0; t < T_; ++t) {
        const unsigned int base = (unsigned int)t * 128u;
        // ------------------------- phase 1: Z and R -------------------------
        {
            f32x4 acc = {0.f, 0.f, 0.f, 0.f};
            // X-part first: independent of the recurrence
            const float* xr = X + (size_t)m1 * (T_ * KIN) + (size_t)t * KIN;
#pragma unroll 4
            for (int j = 0; j < 16; ++j) {
                int kp = j * 32 + fk;
                short8 xhi, xlo; cvt_x8(xr, kp, &xhi, &xlo);
                short8 b3 = *(const short8*)(Bp1 + 1536 + kp);
                short8 b4 = *(const short8*)(Bp1 + 2048 + kp);
                short8 b5 = *(const short8*)(Bp1 + 2560 + kp);
                acc = MFMA(xhi, b3, acc); acc = MFMA(xlo, b4, acc); acc = MFMA(xhi, b5, acc);
            }
            if (tid == 0) {                 // B2(t-1): H(t-1) published
                while (ald32(cnt) < base) __builtin_amdgcn_s_sleep(2);
            }
            __syncthreads();
            // H-part: issue ALL 64 coherent q-loads up-front (compiler tracks
            // vmcnt; static indices keep q[] in registers — rule #20)
            const unsigned int* hp = HP + m1 * NH;
            unsigned long long q[16][4];
#pragma unroll
            for (int j = 0; j < 16; ++j) {
                int kp = j * 32 + fk;
#pragma unroll
                for (int i = 0; i < 4; ++i) q[j][i] = ald64(hp + kp + 2 * i);
            }
#pragma unroll 4
            for (int j = 0; j < 16; ++j) {
                int kp = j * 32 + fk;
                short8 ahi, alo; unpack8(q[j], &ahi, &alo);
                short8 b0 = *(const short8*)(Bp1 + kp);
                short8 b1 = *(const short8*)(Bp1 + 512 + kp);
                short8 b2 = *(const short8*)(Bp1 + 1024 + kp);
                acc = MFMA(ahi, b0, acc); acc = MFMA(alo, b1, acc); acc = MFMA(ahi, b2, acc);
            }
            if (blk < 32) {                 // z-gate columns
                float bzi = bz[c1];
#pragma unroll
                for (int jj = 0; jj < 4; ++jj) {
                    int mrow = wv * 16 + fkc * 4 + jj;
                    float g = 1.f / (1.f + __expf(-(acc[jj] + bzi)));
                    astf(Zbuf + mrow * NH + c1, g);
                }
            } else {                        // r-gate columns -> RH = R*H packed
                int cr = c1 - 512;
                float bri = br[cr];
                unsigned int hw[4];
#pragma unroll
                for (int jj = 0; jj < 4; ++jj)
                    hw[jj] = ald32(HP + (wv * 16 + fkc * 4 + jj) * NH + cr);
#pragma unroll
                for (int jj = 0; jj < 4; ++jj) {
                    int mrow = wv * 16 + fkc * 4 + jj;
                    float h  = b2f((unsigned short)(hw[jj] & 0xffffu)) +
                               b2f((unsigned short)(hw[jj] >> 16));
                    float g  = 1.f / (1.f + __expf(-(acc[jj] + bri)));
                    float rh = g * h;
                    unsigned short hi = f2b(rh);
                    unsigned short lo = f2b(rh - b2f(hi));
                    ast32(RHP + mrow * NH + cr, (unsigned int)hi | ((unsigned int)lo << 16));
                }
            }
        }
        __syncthreads();                    // drains every wave's stores (vmcnt 0)
        if (tid == 0)
            __hip_atomic_fetch_add(cnt, 1u, __ATOMIC_RELAXED, __HIP_MEMORY_SCOPE_AGENT);
        // ------------------------- phase 2: h~ and H update ------------------
        {
            f32x4 acc = {0.f, 0.f, 0.f, 0.f};
            if (khalf == 1) {               // X half: no cross-block dependency
                const float* xr = X + (size_t)m2 * (T_ * KIN) + (size_t)t * KIN;
#pragma unroll 4
                for (int j = 0; j < 16; ++j) {
                    int kp = j * 32 + fk;
                    short8 xhi, xlo; cvt_x8(xr, kp, &xhi, &xlo);
                    short8 b3 = *(const short8*)(Bp2 + 1536 + kp);
                    short8 b4 = *(const short8*)(Bp2 + 2048 + kp);
                    short8 b5 = *(const short8*)(Bp2 + 2560 + kp);
                    acc = MFMA(xhi, b3, acc); acc = MFMA(xlo, b4, acc); acc = MFMA(xhi, b5, acc);
                }
#pragma unroll
                for (int jj = 0; jj < 4; ++jj)
                    comb[slot][(fkc * 4 + jj) * 16 + fm] = acc[jj];
            }
            if (tid == 0) {                 // B1(t): phase 1 complete
                while (ald32(cnt) < base + 64u) __builtin_amdgcn_s_sleep(2);
            }
            __syncthreads();                // joins spin-exit AND comb writes
            if (khalf == 0) {
                const unsigned int* rp = RHP + m2 * NH;
                unsigned long long q[16][4];
#pragma unroll
                for (int j = 0; j < 16; ++j) {
                    int kp = j * 32 + fk;
#pragma unroll
                    for (int i = 0; i < 4; ++i) q[j][i] = ald64(rp + kp + 2 * i);
                }
#pragma unroll 4
                for (int j = 0; j < 16; ++j) {
                    int kp = j * 32 + fk;
                    short8 ahi, alo; unpack8(q[j], &ahi, &alo);
                    short8 b0 = *(const short8*)(Bp2 + kp);
                    short8 b1 = *(const short8*)(Bp2 + 512 + kp);
                    short8 b2 = *(const short8*)(Bp2 + 1024 + kp);
                    acc = MFMA(ahi, b0, acc); acc = MFMA(alo, b1, acc); acc = MFMA(ahi, b2, acc);
                }
                float zv[4];
                unsigned int hw[4];
#pragma unroll
                for (int jj = 0; jj < 4; ++jj) {
                    int mrow = mt2 * 16 + fkc * 4 + jj;
                    zv[jj] = aldf(Zbuf + mrow * NH + c2);
                    hw[jj] = ald32(HP + mrow * NH + c2);
                }
                float bhi = bh[c2];
#pragma unroll
                for (int jj = 0; jj < 4; ++jj) {
                    int mrow = mt2 * 16 + fkc * 4 + jj;
                    float pre = acc[jj] + comb[slot][(fkc * 4 + jj) * 16 + fm] + bhi;
                    float e  = __expf(-2.f * pre);
                    float ht = 2.f / (1.f + e) - 1.f;   // tanh
                    float h  = b2f((unsigned short)(hw[jj] & 0xffffu)) +
                               b2f((unsigned short)(hw[jj] >> 16));
                    float hn = zv[jj] * h + (1.f - zv[jj]) * ht;
                    out[(size_t)mrow * (T_ * NH) + (size_t)t * NH + c2] = hn;
                    if (t == T_ - 1)
                        out[(size_t)B_ * T_ * NH + mrow * NH + c2] = hn;
                    unsigned short hi = f2b(hn);
                    unsigned short lo = f2b(hn - b2f(hi));
                    ast32(HP + mrow * NH + c2, (unsigned int)hi | ((unsigned int)lo << 16));
                }
            }
        }
        __syncthreads();                    // drains stores
        if (tid == 0)
            __hip_atomic_fetch_add(cnt, 1u, __ATOMIC_RELAXED, __HIP_MEMORY_SCOPE_AGENT);
    }
}

extern "C" void kernel_launch(void* const* d_in, const int* in_sizes, int n_in,
                              void* d_out, int out_size, void* d_ws, size_t ws_size,
                              hipStream_t stream) {
    (void)in_sizes; (void)n_in; (void)out_size; (void)ws_size;
    const float* X   = (const float*)d_in[0];
    const float* Wxz = (const float*)d_in[1];
    const float* Whz = (const float*)d_in[2];
    const float* bz  = (const float*)d_in[3];
    const float* Wxr = (const float*)d_in[4];
    const float* Whr = (const float*)d_in[5];
    const float* br  = (const float*)d_in[6];
    const float* Wxh = (const float*)d_in[7];
    const float* Whh = (const float*)d_in[8];
    const float* bh  = (const float*)d_in[9];
    float* out = (float*)d_out;

    char* ws = (char*)d_ws;
    unsigned int* cnt = (unsigned int*)ws;                        // 256 B
    float* Zbuf       = (float*)(ws + 256);                       // 128 KB
    unsigned int* HP  = (unsigned int*)(ws + 256 + 131072);       // 128 KB packed
    unsigned int* RHP = (unsigned int*)(ws + 256 + 262144);       // 128 KB packed
    unsigned short* Bzr = (unsigned short*)(ws + (1 << 20));      // 6.3 MB
    unsigned short* Bh  = Bzr + (size_t)1024 * KEFF;              // 3.2 MB

    // zero barrier counter + H0 state each call (graph-replay safe)
    hipMemsetAsync(d_ws, 0, 1 << 20, stream);
    prepack<<<dim3(12, 1536), 256, 0, stream>>>(Wxz, Whz, Wxr, Whr, Wxh, Whh, Bzr, Bh);
    gru_seq<<<NBLK, NTHR, 0, stream>>>(X, bz, br, bh, out, Zbuf, HP, RHP, Bzr, Bh, cnt);
}

// Round 4
// 15586.887 us; speedup vs baseline: 1.9041x; 1.9041x over previous
//
#include <hip/hip_runtime.h>

#define B_   64
#define T_   512
#define KIN  512
#define NH   512
#define KEFF 3072   // 6 segments x 512
#define NBLK 64
#define NTHR 256

typedef __attribute__((ext_vector_type(8))) short short8;
typedef __attribute__((ext_vector_type(4))) float f32x4;
typedef __attribute__((ext_vector_type(4))) unsigned int u32x4;

// bf16 round-to-nearest-even via bit ops
__device__ __forceinline__ unsigned short f2b(float f) {
    union { float f; unsigned int u; } v; v.f = f;
    unsigned int u = v.u;
    return (unsigned short)((u + 0x7FFFu + ((u >> 16) & 1u)) >> 16);
}
__device__ __forceinline__ float b2f(unsigned short h) {
    union { float f; unsigned int u; } v; v.u = ((unsigned int)h) << 16;
    return v.f;
}

// ---------------------------------------------------------------------------
// Prepack (proven): B' [n][keff] bf16. Segments:
//   seg0: Whi(H) seg1: Whi(H) seg2: Wlo(H) seg3: Whi(X) seg4: Whi(X) seg5: Wlo(X)
// ---------------------------------------------------------------------------
__global__ void prepack(const float* __restrict__ Wxz, const float* __restrict__ Whz,
                        const float* __restrict__ Wxr, const float* __restrict__ Whr,
                        const float* __restrict__ Wxh, const float* __restrict__ Whh,
                        unsigned short* __restrict__ Bzr, unsigned short* __restrict__ Bh) {
    int keff = blockIdx.x * 256 + threadIdx.x;  // 0..3071
    int n    = blockIdx.y;                      // 0..1535
    int seg  = keff >> 9;
    int k    = keff & 511;
    const float* src;
    int c;
    if (n < 512)       { c = n;        src = (seg < 3) ? Whz : Wxz; }
    else if (n < 1024) { c = n - 512;  src = (seg < 3) ? Whr : Wxr; }
    else               { c = n - 1024; src = (seg < 3) ? Whh : Wxh; }
    float w = src[k * NH + c];
    unsigned short hi = f2b(w);
    unsigned short o  = (seg == 2 || seg == 5) ? f2b(w - b2f(hi)) : hi;
    if (n < 1024) Bzr[(size_t)n * KEFF + keff] = o;
    else          Bh[(size_t)(n - 1024) * KEFF + keff] = o;
}

// Coherent ops (proven round 3): relaxed+agent -> sc-bit loads/stores, no
// cache-maintenance instructions anywhere.
__device__ __forceinline__ unsigned int ald32(const unsigned int* p) {
    return __hip_atomic_load(p, __ATOMIC_RELAXED, __HIP_MEMORY_SCOPE_AGENT);
}
__device__ __forceinline__ unsigned long long ald64(const void* p) {
    return __hip_atomic_load((const unsigned long long*)p, __ATOMIC_RELAXED,
                             __HIP_MEMORY_SCOPE_AGENT);
}
__device__ __forceinline__ void ast32(unsigned int* p, unsigned int v) {
    __hip_atomic_store(p, v, __ATOMIC_RELAXED, __HIP_MEMORY_SCOPE_AGENT);
}
__device__ __forceinline__ void ast64(void* p, unsigned long long v) {
    __hip_atomic_store((unsigned long long*)p, v, __ATOMIC_RELAXED,
                       __HIP_MEMORY_SCOPE_AGENT);
}

// XOR-permuted global word index for HP/RHP: row-major [64][512] u32 with
// within-row swizzle so gload_lds(linear) + swizzled ds_read is conflict-light.
__device__ __forceinline__ int hp_idx(int m, int c) {
    return m * 512 + (c ^ ((m & 7) << 2));
}

// fp32 -> bf16 hi/lo split of 8 consecutive X elements
__device__ __forceinline__ void cvt_x8(const float* xr, int kp, short8* ahi, short8* alo) {
    f32x4 x0 = *(const f32x4*)(xr + kp);
    f32x4 x1 = *(const f32x4*)(xr + kp + 4);
#pragma unroll
    for (int i = 0; i < 4; ++i) {
        unsigned short h0 = f2b(x0[i]);
        (*ahi)[i] = (short)h0; (*alo)[i] = (short)f2b(x0[i] - b2f(h0));
        unsigned short h1 = f2b(x1[i]);
        (*ahi)[4 + i] = (short)h1; (*alo)[4 + i] = (short)f2b(x1[i] - b2f(h1));
    }
}

// 8 packed u32 (hi|lo<<16) -> hi/lo short8 fragments
__device__ __forceinline__ void unpackw(u32x4 w0, u32x4 w1, short8* ahi, short8* alo) {
    union { unsigned int u[4]; short8 v; } H, L;
    H.u[0] = __builtin_amdgcn_perm(w0[1], w0[0], 0x05040100u);
    H.u[1] = __builtin_amdgcn_perm(w0[3], w0[2], 0x05040100u);
    H.u[2] = __builtin_amdgcn_perm(w1[1], w1[0], 0x05040100u);
    H.u[3] = __builtin_amdgcn_perm(w1[3], w1[2], 0x05040100u);
    L.u[0] = __builtin_amdgcn_perm(w0[1], w0[0], 0x07060302u);
    L.u[1] = __builtin_amdgcn_perm(w0[3], w0[2], 0x07060302u);
    L.u[2] = __builtin_amdgcn_perm(w1[1], w1[0], 0x07060302u);
    L.u[3] = __builtin_amdgcn_perm(w1[3], w1[2], 0x07060302u);
    *ahi = H.v; *alo = L.v;
}

#define MFMA(a, b, c) __builtin_amdgcn_mfma_f32_16x16x32_bf16((a), (b), (c), 0, 0, 0)

// ---------------------------------------------------------------------------
// Persistent GRU. 64 blocks x 256 threads, 1 block/CU (LDS 133 KB).
// Cross-block state (HP/RHP packed u32, Zt [c][m] f32) moves via MALL:
// producers ast32/ast64 (agent), consumers gload_lds(aux=sc0|sc1) -> LDS.
// ---------------------------------------------------------------------------
__global__ void __launch_bounds__(NTHR, 1) gru_seq(
    const float* __restrict__ X, const float* __restrict__ bz,
    const float* __restrict__ br, const float* __restrict__ bh,
    float* __restrict__ out, float* __restrict__ Zt,
    unsigned int* __restrict__ HP, unsigned int* __restrict__ RHP,
    const unsigned short* __restrict__ Bzr, const unsigned short* __restrict__ Bh,
    unsigned int* cnt) {
    const int blk  = blockIdx.x;
    const int tid  = threadIdx.x;
    const int wv   = tid >> 6;
    const int lane = tid & 63;
    const int fm   = lane & 15;      // A-row / B-col / C-col within 16
    const int fkc  = lane >> 4;      // k-chunk 0..3
    const int fk   = fkc * 8;

    __shared__ unsigned int hbuf[4 * 16 * 512];  // 128 KB: 4 slices x 16 rows x 2 KB
    __shared__ float comb[2][256];

    // phase-1 geometry: block owns zr-ntile blk, wave owns mtile wv
    const int m1 = wv * 16 + fm;
    const unsigned short* Bp1 = Bzr + (size_t)(blk * 16 + fm) * KEFF;
    const int c1 = blk * 16 + fm;    // zr col (block-uniform z vs r)

    // phase-2 geometry: block -> mtile (blk&3), ntiles 2*(blk>>2)+{0,1}
    const int mt    = blk & 3;
    const int slot  = wv >> 1;
    const int khalf = wv & 1;        // 0: RH half, 1: X half
    const int nt    = (blk >> 2) * 2 + slot;
    const int m2    = mt * 16 + fm;
    const unsigned short* Bp2 = Bh + (size_t)(nt * 16 + fm) * KEFF;
    const int c2 = nt * 16 + fm;

    const int key = (fm & 7) << 4;           // ds_read swizzle (matches hp_idx)
    const int sw0 = (32 * fkc) ^ key;
    const int sw1 = (32 * fkc + 16) ^ key;

    const char* HPb  = (const char*)HP;
    const char* RHPb = (const char*)RHP;

    for (int t = 0; t < T_; ++t) {
        const unsigned int base = (unsigned int)t * 128u;
        // ------------------------- phase 1: Z and R -------------------------
        {
            f32x4 acc = {0.f, 0.f, 0.f, 0.f};
            // X-part first: independent of recurrence, hides barrier skew
            const float* xr = X + (size_t)m1 * (T_ * KIN) + (size_t)t * KIN;
#pragma unroll 4
            for (int j = 0; j < 16; ++j) {
                int kp = j * 32 + fk;
                short8 xhi, xlo; cvt_x8(xr, kp, &xhi, &xlo);
                short8 b3 = *(const short8*)(Bp1 + 1536 + kp);
                short8 b4 = *(const short8*)(Bp1 + 2048 + kp);
                short8 b5 = *(const short8*)(Bp1 + 2560 + kp);
                acc = MFMA(xhi, b3, acc); acc = MFMA(xlo, b4, acc); acc = MFMA(xhi, b5, acc);
            }
            if (tid == 0 && t) {            // B2(t-1): H(t-1) published
                while (ald32(cnt) < base) __builtin_amdgcn_s_sleep(2);
            }
            __syncthreads();
            // stage own 32 KB H slice (rows [16wv,16wv+16)) -> LDS, coherent
            {
                const char* src = HPb + wv * 32768;
                char* dst = (char*)hbuf + wv * 32768;
#pragma unroll
                for (int i = 0; i < 32; ++i)
                    __builtin_amdgcn_global_load_lds(
                        (const unsigned int*)(src + i * 1024 + lane * 16),
                        (unsigned int*)(dst + i * 1024), 16, 0, 0x11);
            }
            asm volatile("s_waitcnt vmcnt(0)" ::: "memory");
            __builtin_amdgcn_sched_barrier(0);
            // H-GEMM from LDS (swizzled ds_read_b128 pairs)
            {
                const char* sl = (const char*)hbuf + wv * 32768 + fm * 2048;
#pragma unroll 4
                for (int j = 0; j < 16; ++j) {
                    u32x4 w0 = *(const u32x4*)(sl + 128 * j + sw0);
                    u32x4 w1 = *(const u32x4*)(sl + 128 * j + sw1);
                    short8 ahi, alo; unpackw(w0, w1, &ahi, &alo);
                    int kp = j * 32 + fk;
                    short8 b0 = *(const short8*)(Bp1 + kp);
                    short8 b1 = *(const short8*)(Bp1 + 512 + kp);
                    short8 b2 = *(const short8*)(Bp1 + 1024 + kp);
                    acc = MFMA(ahi, b0, acc); acc = MFMA(alo, b1, acc); acc = MFMA(ahi, b2, acc);
                }
            }
            if (blk < 32) {                 // z-gate -> Zt [c][m], 2x ast64
                float bzi = bz[c1];
                float g[4];
#pragma unroll
                for (int jj = 0; jj < 4; ++jj)
                    g[jj] = 1.f / (1.f + __expf(-(acc[jj] + bzi)));
                union { float f[2]; unsigned long long q; } p0, p1;
                p0.f[0] = g[0]; p0.f[1] = g[1];
                p1.f[0] = g[2]; p1.f[1] = g[3];
                float* zp = Zt + c1 * 64 + wv * 16 + fkc * 4;
                ast64(zp, p0.q); ast64(zp + 2, p1.q);
            } else {                        // r-gate -> RH packed (H from LDS)
                int cr = c1 - 512;
                float bri = br[cr];
#pragma unroll
                for (int jj = 0; jj < 4; ++jj) {
                    int lr = fkc * 4 + jj;
                    unsigned int hw = *(const unsigned int*)((const char*)hbuf +
                        wv * 32768 + lr * 2048 + ((4 * cr) ^ ((lr & 7) << 4)));
                    float h  = b2f((unsigned short)(hw & 0xffffu)) +
                               b2f((unsigned short)(hw >> 16));
                    float gr = 1.f / (1.f + __expf(-(acc[jj] + bri)));
                    float rh = gr * h;
                    unsigned short hi = f2b(rh);
                    unsigned short lo = f2b(rh - b2f(hi));
                    ast32(RHP + hp_idx(wv * 16 + lr, cr),
                          (unsigned int)hi | ((unsigned int)lo << 16));
                }
            }
        }
        __syncthreads();                    // drains stores (vmcnt 0 pre-barrier)
        if (tid == 0)
            __hip_atomic_fetch_add(cnt, 1u, __ATOMIC_RELAXED, __HIP_MEMORY_SCOPE_AGENT);
        // ------------------------- phase 2: h~ and H update ------------------
        {
            f32x4 acc2 = {0.f, 0.f, 0.f, 0.f};
            if (khalf == 1) {               // X half: no cross-block dependency
                const float* xr = X + (size_t)m2 * (T_ * KIN) + (size_t)t * KIN;
#pragma unroll 4
                for (int j = 0; j < 16; ++j) {
                    int kp = j * 32 + fk;
                    short8 xhi, xlo; cvt_x8(xr, kp, &xhi, &xlo);
                    short8 b3 = *(const short8*)(Bp2 + 1536 + kp);
                    short8 b4 = *(const short8*)(Bp2 + 2048 + kp);
                    short8 b5 = *(const short8*)(Bp2 + 2560 + kp);
                    acc2 = MFMA(xhi, b3, acc2); acc2 = MFMA(xlo, b4, acc2); acc2 = MFMA(xhi, b5, acc2);
                }
#pragma unroll
                for (int jj = 0; jj < 4; ++jj)
                    comb[slot][(fkc * 4 + jj) * 16 + fm] = acc2[jj];
            }
            if (tid == 0) {                 // B1(t): phase 1 complete
                while (ald32(cnt) < base + 64u) __builtin_amdgcn_s_sleep(2);
            }
            __syncthreads();                // joins spin-exit AND comb writes
            // prefetch Z (hides MALL latency under staging + GEMM)
            unsigned long long zq0 = 0, zq1 = 0;
            if (khalf == 0) {
                const float* zp = Zt + c2 * 64 + mt * 16 + fkc * 4;
                zq0 = ald64(zp); zq1 = ald64(zp + 2);
            }
            // stage RH rows [16mt,16mt+16) -> slice (mt+2)&3 (keeps slice mt = H)
            {
                const char* src = RHPb + mt * 32768;
                char* dst = (char*)hbuf + ((mt + 2) & 3) * 32768;
#pragma unroll
                for (int i = 0; i < 8; ++i) {
                    int o = (wv * 8 + i) * 1024;
                    __builtin_amdgcn_global_load_lds(
                        (const unsigned int*)(src + o + lane * 16),
                        (unsigned int*)(dst + o), 16, 0, 0x11);
                }
            }
            asm volatile("s_waitcnt vmcnt(0)" ::: "memory");
            __builtin_amdgcn_sched_barrier(0);
            __syncthreads();                // cross-wave staged data visible
            if (khalf == 0) {
                const char* sl = (const char*)hbuf + ((mt + 2) & 3) * 32768 + fm * 2048;
#pragma unroll 4
                for (int j = 0; j < 16; ++j) {
                    u32x4 w0 = *(const u32x4*)(sl + 128 * j + sw0);
                    u32x4 w1 = *(const u32x4*)(sl + 128 * j + sw1);
                    short8 ahi, alo; unpackw(w0, w1, &ahi, &alo);
                    int kp = j * 32 + fk;
                    short8 b0 = *(const short8*)(Bp2 + kp);
                    short8 b1 = *(const short8*)(Bp2 + 512 + kp);
                    short8 b2 = *(const short8*)(Bp2 + 1024 + kp);
                    acc2 = MFMA(ahi, b0, acc2); acc2 = MFMA(alo, b1, acc2); acc2 = MFMA(ahi, b2, acc2);
                }
                union { unsigned long long q; float f[2]; } z0, z1;
                z0.q = zq0; z1.q = zq1;
                float zv[4] = {z0.f[0], z0.f[1], z1.f[0], z1.f[1]};
                float bhi = bh[c2];
#pragma unroll
                for (int jj = 0; jj < 4; ++jj) {
                    int lr   = fkc * 4 + jj;
                    int mrow = mt * 16 + lr;
                    unsigned int hw = *(const unsigned int*)((const char*)hbuf +
                        mt * 32768 + lr * 2048 + ((4 * c2) ^ ((lr & 7) << 4)));
                    float h   = b2f((unsigned short)(hw & 0xffffu)) +
                                b2f((unsigned short)(hw >> 16));
                    float pre = acc2[jj] + comb[slot][lr * 16 + fm] + bhi;
                    float e   = __expf(-2.f * pre);
                    float ht  = 2.f / (1.f + e) - 1.f;   // tanh
                    float hn  = zv[jj] * h + (1.f - zv[jj]) * ht;
                    out[(size_t)mrow * (T_ * NH) + (size_t)t * NH + c2] = hn;
                    if (t == T_ - 1)
                        out[(size_t)B_ * T_ * NH + mrow * NH + c2] = hn;
                    unsigned short hi = f2b(hn);
                    unsigned short lo = f2b(hn - b2f(hi));
                    ast32(HP + hp_idx(mrow, c2),
                          (unsigned int)hi | ((unsigned int)lo << 16));
                }
            }
        }
        __syncthreads();                    // drains stores
        if (tid == 0)
            __hip_atomic_fetch_add(cnt, 1u, __ATOMIC_RELAXED, __HIP_MEMORY_SCOPE_AGENT);
    }
}

extern "C" void kernel_launch(void* const* d_in, const int* in_sizes, int n_in,
                              void* d_out, int out_size, void* d_ws, size_t ws_size,
                              hipStream_t stream) {
    (void)in_sizes; (void)n_in; (void)out_size; (void)ws_size;
    const float* X   = (const float*)d_in[0];
    const float* Wxz = (const float*)d_in[1];
    const float* Whz = (const float*)d_in[2];
    const float* bz  = (const float*)d_in[3];
    const float* Wxr = (const float*)d_in[4];
    const float* Whr = (const float*)d_in[5];
    const float* br  = (const float*)d_in[6];
    const float* Wxh = (const float*)d_in[7];
    const float* Whh = (const float*)d_in[8];
    const float* bh  = (const float*)d_in[9];
    float* out = (float*)d_out;

    char* ws = (char*)d_ws;
    unsigned int* cnt = (unsigned int*)ws;                        // 256 B
    float* Zt         = (float*)(ws + 256);                       // 128 KB [c][m]
    unsigned int* HP  = (unsigned int*)(ws + 256 + 131072);       // 128 KB packed+swz
    unsigned int* RHP = (unsigned int*)(ws + 256 + 262144);       // 128 KB packed+swz
    unsigned short* Bzr = (unsigned short*)(ws + (1 << 20));      // 6.3 MB
    unsigned short* Bh  = Bzr + (size_t)1024 * KEFF;              // 3.2 MB

    // zero barrier counter + H0 state each call (graph-replay safe)
    hipMemsetAsync(d_ws, 0, 1 << 20, stream);
    prepack<<<dim3(12, 1536), 256, 0, stream>>>(Wxz, Whz, Wxr, Whr, Wxh, Whh, Bzr, Bh);
    gru_seq<<<NBLK, NTHR, 0, stream>>>(X, bz, br, bh, out, Zt, HP, RHP, Bzr, Bh, cnt);
}

// Round 5
// 14782.648 us; speedup vs baseline: 2.0076x; 1.0544x over previous
//
#include <hip/hip_runtime.h>

#define B_   64
#define T_   512
#define KIN  512
#define NH   512
#define KEFF 3072   // 6 segments x 512
#define NBLK 64
#define NTHR 256

typedef __attribute__((ext_vector_type(8))) short short8;
typedef __attribute__((ext_vector_type(4))) float f32x4;
typedef __attribute__((ext_vector_type(4))) unsigned int u32x4;

// bf16 round-to-nearest-even via bit ops
__device__ __forceinline__ unsigned short f2b(float f) {
    union { float f; unsigned int u; } v; v.f = f;
    unsigned int u = v.u;
    return (unsigned short)((u + 0x7FFFu + ((u >> 16) & 1u)) >> 16);
}
__device__ __forceinline__ float b2f(unsigned short h) {
    union { float f; unsigned int u; } v; v.u = ((unsigned int)h) << 16;
    return v.f;
}

// ---------------------------------------------------------------------------
// Prepack (proven): B' [n][keff] bf16. Segments:
//   seg0: Whi(H) seg1: Whi(H) seg2: Wlo(H) seg3: Whi(X) seg4: Whi(X) seg5: Wlo(X)
// ---------------------------------------------------------------------------
__global__ void prepack(const float* __restrict__ Wxz, const float* __restrict__ Whz,
                        const float* __restrict__ Wxr, const float* __restrict__ Whr,
                        const float* __restrict__ Wxh, const float* __restrict__ Whh,
                        unsigned short* __restrict__ Bzr, unsigned short* __restrict__ Bh) {
    int keff = blockIdx.x * 256 + threadIdx.x;  // 0..3071
    int n    = blockIdx.y;                      // 0..1535
    int seg  = keff >> 9;
    int k    = keff & 511;
    const float* src;
    int c;
    if (n < 512)       { c = n;        src = (seg < 3) ? Whz : Wxz; }
    else if (n < 1024) { c = n - 512;  src = (seg < 3) ? Whr : Wxr; }
    else               { c = n - 1024; src = (seg < 3) ? Whh : Wxh; }
    float w = src[k * NH + c];
    unsigned short hi = f2b(w);
    unsigned short o  = (seg == 2 || seg == 5) ? f2b(w - b2f(hi)) : hi;
    if (n < 1024) Bzr[(size_t)n * KEFF + keff] = o;
    else          Bh[(size_t)(n - 1024) * KEFF + keff] = o;
}

// Coherent ops (proven): relaxed+agent -> sc-bit loads/stores, no cache
// maintenance anywhere -> weights stay L2-warm all 512 steps.
__device__ __forceinline__ unsigned int ald32(const unsigned int* p) {
    return __hip_atomic_load(p, __ATOMIC_RELAXED, __HIP_MEMORY_SCOPE_AGENT);
}
__device__ __forceinline__ unsigned long long ald64(const void* p) {
    return __hip_atomic_load((const unsigned long long*)p, __ATOMIC_RELAXED,
                             __HIP_MEMORY_SCOPE_AGENT);
}
__device__ __forceinline__ void ast32(unsigned int* p, unsigned int v) {
    __hip_atomic_store(p, v, __ATOMIC_RELAXED, __HIP_MEMORY_SCOPE_AGENT);
}
__device__ __forceinline__ void ast64(void* p, unsigned long long v) {
    __hip_atomic_store((unsigned long long*)p, v, __ATOMIC_RELAXED,
                       __HIP_MEMORY_SCOPE_AGENT);
}

// Flag barrier: NO same-address atomic RMW (round-4's 64 serialized
// fetch_adds per barrier ~= the 13us/barrier stall). Arrival = store own
// slot; wait = wave-0 64-lane coalesced poll of all 64 flags + __all vote.
__device__ __forceinline__ void flag_wait(const unsigned int* flags,
                                          unsigned int tgt, int lane) {
    while (1) {
        unsigned int v = ald32(flags + lane);   // lane l polls block l's flag
        if (__all((int)(v >= tgt))) break;
    }
    __builtin_amdgcn_sched_barrier(0);
}

// XOR-permuted global word index for HP/RHP (matches linear gload_lds +
// swizzled ds_read).
__device__ __forceinline__ int hp_idx(int m, int c) {
    return m * 512 + (c ^ ((m & 7) << 2));
}

// fp32 -> bf16 hi/lo split of 8 consecutive X elements
__device__ __forceinline__ void cvt_x8(const float* xr, int kp, short8* ahi, short8* alo) {
    f32x4 x0 = *(const f32x4*)(xr + kp);
    f32x4 x1 = *(const f32x4*)(xr + kp + 4);
#pragma unroll
    for (int i = 0; i < 4; ++i) {
        unsigned short h0 = f2b(x0[i]);
        (*ahi)[i] = (short)h0; (*alo)[i] = (short)f2b(x0[i] - b2f(h0));
        unsigned short h1 = f2b(x1[i]);
        (*ahi)[4 + i] = (short)h1; (*alo)[4 + i] = (short)f2b(x1[i] - b2f(h1));
    }
}

// 8 packed u32 (hi|lo<<16) -> hi/lo short8 fragments
__device__ __forceinline__ void unpackw(u32x4 w0, u32x4 w1, short8* ahi, short8* alo) {
    union { unsigned int u[4]; short8 v; } H, L;
    H.u[0] = __builtin_amdgcn_perm(w0[1], w0[0], 0x05040100u);
    H.u[1] = __builtin_amdgcn_perm(w0[3], w0[2], 0x05040100u);
    H.u[2] = __builtin_amdgcn_perm(w1[1], w1[0], 0x05040100u);
    H.u[3] = __builtin_amdgcn_perm(w1[3], w1[2], 0x05040100u);
    L.u[0] = __builtin_amdgcn_perm(w0[1], w0[0], 0x07060302u);
    L.u[1] = __builtin_amdgcn_perm(w0[3], w0[2], 0x07060302u);
    L.u[2] = __builtin_amdgcn_perm(w1[1], w1[0], 0x07060302u);
    L.u[3] = __builtin_amdgcn_perm(w1[3], w1[2], 0x07060302u);
    *ahi = H.v; *alo = L.v;
}

#define MFMA(a, b, c) __builtin_amdgcn_mfma_f32_16x16x32_bf16((a), (b), (c), 0, 0, 0)

// ---------------------------------------------------------------------------
// Persistent GRU. 64 blocks x 256 threads, 1 block/CU (LDS 133 KB).
// Identical to round-4 (passed, absmax 0.0039) except the grid barrier.
// Epochs: flags[blk] = 2t+1 after phase 1, 2t+2 after phase 2.
// ---------------------------------------------------------------------------
__global__ void __launch_bounds__(NTHR, 1) gru_seq(
    const float* __restrict__ X, const float* __restrict__ bz,
    const float* __restrict__ br, const float* __restrict__ bh,
    float* __restrict__ out, float* __restrict__ Zt,
    unsigned int* __restrict__ HP, unsigned int* __restrict__ RHP,
    const unsigned short* __restrict__ Bzr, const unsigned short* __restrict__ Bh,
    unsigned int* flags) {
    const int blk  = blockIdx.x;
    const int tid  = threadIdx.x;
    const int wv   = tid >> 6;
    const int lane = tid & 63;
    const int fm   = lane & 15;      // A-row / B-col / C-col within 16
    const int fkc  = lane >> 4;      // k-chunk 0..3
    const int fk   = fkc * 8;

    __shared__ unsigned int hbuf[4 * 16 * 512];  // 128 KB: 4 slices x 16 rows x 2 KB
    __shared__ float comb[2][256];

    // phase-1 geometry: block owns zr-ntile blk, wave owns mtile wv
    const int m1 = wv * 16 + fm;
    const unsigned short* Bp1 = Bzr + (size_t)(blk * 16 + fm) * KEFF;
    const int c1 = blk * 16 + fm;    // zr col (block-uniform z vs r)

    // phase-2 geometry: block -> mtile (blk&3), ntiles 2*(blk>>2)+{0,1}
    const int mt    = blk & 3;
    const int slot  = wv >> 1;
    const int khalf = wv & 1;        // 0: RH half, 1: X half
    const int nt    = (blk >> 2) * 2 + slot;
    const int m2    = mt * 16 + fm;
    const unsigned short* Bp2 = Bh + (size_t)(nt * 16 + fm) * KEFF;
    const int c2 = nt * 16 + fm;

    const int key = (fm & 7) << 4;           // ds_read swizzle (matches hp_idx)
    const int sw0 = (32 * fkc) ^ key;
    const int sw1 = (32 * fkc + 16) ^ key;

    const char* HPb  = (const char*)HP;
    const char* RHPb = (const char*)RHP;

    for (int t = 0; t < T_; ++t) {
        const unsigned int ep = (unsigned int)t * 2u;
        // ------------------------- phase 1: Z and R -------------------------
        {
            f32x4 acc = {0.f, 0.f, 0.f, 0.f};
            // X-part first: independent of recurrence, overlaps others' phase 2
            const float* xr = X + (size_t)m1 * (T_ * KIN) + (size_t)t * KIN;
#pragma unroll 4
            for (int j = 0; j < 16; ++j) {
                int kp = j * 32 + fk;
                short8 xhi, xlo; cvt_x8(xr, kp, &xhi, &xlo);
                short8 b3 = *(const short8*)(Bp1 + 1536 + kp);
                short8 b4 = *(const short8*)(Bp1 + 2048 + kp);
                short8 b5 = *(const short8*)(Bp1 + 2560 + kp);
                acc = MFMA(xhi, b3, acc); acc = MFMA(xlo, b4, acc); acc = MFMA(xhi, b5, acc);
            }
            if (wv == 0 && t) flag_wait(flags, ep, lane);   // H(t-1) published
            __syncthreads();
            // stage own 32 KB H slice (rows [16wv,16wv+16)) -> LDS, coherent
            {
                const char* src = HPb + wv * 32768;
                char* dst = (char*)hbuf + wv * 32768;
#pragma unroll
                for (int i = 0; i < 32; ++i)
                    __builtin_amdgcn_global_load_lds(
                        (const unsigned int*)(src + i * 1024 + lane * 16),
                        (unsigned int*)(dst + i * 1024), 16, 0, 0x11);
            }
            asm volatile("s_waitcnt vmcnt(0)" ::: "memory");
            __builtin_amdgcn_sched_barrier(0);
            // H-GEMM from LDS (swizzled ds_read_b128 pairs)
            {
                const char* sl = (const char*)hbuf + wv * 32768 + fm * 2048;
#pragma unroll 4
                for (int j = 0; j < 16; ++j) {
                    u32x4 w0 = *(const u32x4*)(sl + 128 * j + sw0);
                    u32x4 w1 = *(const u32x4*)(sl + 128 * j + sw1);
                    short8 ahi, alo; unpackw(w0, w1, &ahi, &alo);
                    int kp = j * 32 + fk;
                    short8 b0 = *(const short8*)(Bp1 + kp);
                    short8 b1 = *(const short8*)(Bp1 + 512 + kp);
                    short8 b2 = *(const short8*)(Bp1 + 1024 + kp);
                    acc = MFMA(ahi, b0, acc); acc = MFMA(alo, b1, acc); acc = MFMA(ahi, b2, acc);
                }
            }
            if (blk < 32) {                 // z-gate -> Zt [c][m], 2x ast64
                float bzi = bz[c1];
                float g[4];
#pragma unroll
                for (int jj = 0; jj < 4; ++jj)
                    g[jj] = 1.f / (1.f + __expf(-(acc[jj] + bzi)));
                union { float f[2]; unsigned long long q; } p0, p1;
                p0.f[0] = g[0]; p0.f[1] = g[1];
                p1.f[0] = g[2]; p1.f[1] = g[3];
                float* zp = Zt + c1 * 64 + wv * 16 + fkc * 4;
                ast64(zp, p0.q); ast64(zp + 2, p1.q);
            } else {                        // r-gate -> RH packed (H from LDS)
                int cr = c1 - 512;
                float bri = br[cr];
#pragma unroll
                for (int jj = 0; jj < 4; ++jj) {
                    int lr = fkc * 4 + jj;
                    unsigned int hw = *(const unsigned int*)((const char*)hbuf +
                        wv * 32768 + lr * 2048 + ((4 * cr) ^ ((lr & 7) << 4)));
                    float h  = b2f((unsigned short)(hw & 0xffffu)) +
                               b2f((unsigned short)(hw >> 16));
                    float gr = 1.f / (1.f + __expf(-(acc[jj] + bri)));
                    float rh = gr * h;
                    unsigned short hi = f2b(rh);
                    unsigned short lo = f2b(rh - b2f(hi));
                    ast32(RHP + hp_idx(wv * 16 + lr, cr),
                          (unsigned int)hi | ((unsigned int)lo << 16));
                }
            }
        }
        __syncthreads();                    // drains stores (vmcnt 0 pre-barrier)
        if (tid == 0) ast32(flags + blk, ep + 1u);   // B1 arrive: own slot
        // ------------------------- phase 2: h~ and H update ------------------
        {
            f32x4 acc2 = {0.f, 0.f, 0.f, 0.f};
            if (khalf == 1) {               // X half: no cross-block dependency
                const float* xr = X + (size_t)m2 * (T_ * KIN) + (size_t)t * KIN;
#pragma unroll 4
                for (int j = 0; j < 16; ++j) {
                    int kp = j * 32 + fk;
                    short8 xhi, xlo; cvt_x8(xr, kp, &xhi, &xlo);
                    short8 b3 = *(const short8*)(Bp2 + 1536 + kp);
                    short8 b4 = *(const short8*)(Bp2 + 2048 + kp);
                    short8 b5 = *(const short8*)(Bp2 + 2560 + kp);
                    acc2 = MFMA(xhi, b3, acc2); acc2 = MFMA(xlo, b4, acc2); acc2 = MFMA(xhi, b5, acc2);
                }
#pragma unroll
                for (int jj = 0; jj < 4; ++jj)
                    comb[slot][(fkc * 4 + jj) * 16 + fm] = acc2[jj];
            }
            if (wv == 0) flag_wait(flags, ep + 1u, lane);   // phase 1 complete
            __syncthreads();                // joins spin-exit AND comb writes
            // prefetch Z (hides MALL latency under staging + GEMM)
            unsigned long long zq0 = 0, zq1 = 0;
            if (khalf == 0) {
                const float* zp = Zt + c2 * 64 + mt * 16 + fkc * 4;
                zq0 = ald64(zp); zq1 = ald64(zp + 2);
            }
            // stage RH rows [16mt,16mt+16) -> slice (mt+2)&3 (keeps slice mt = H)
            {
                const char* src = RHPb + mt * 32768;
                char* dst = (char*)hbuf + ((mt + 2) & 3) * 32768;
#pragma unroll
                for (int i = 0; i < 8; ++i) {
                    int o = (wv * 8 + i) * 1024;
                    __builtin_amdgcn_global_load_lds(
                        (const unsigned int*)(src + o + lane * 16),
                        (unsigned int*)(dst + o), 16, 0, 0x11);
                }
            }
            asm volatile("s_waitcnt vmcnt(0)" ::: "memory");
            __builtin_amdgcn_sched_barrier(0);
            __syncthreads();                // cross-wave staged data visible
            if (khalf == 0) {
                const char* sl = (const char*)hbuf + ((mt + 2) & 3) * 32768 + fm * 2048;
#pragma unroll 4
                for (int j = 0; j < 16; ++j) {
                    u32x4 w0 = *(const u32x4*)(sl + 128 * j + sw0);
                    u32x4 w1 = *(const u32x4*)(sl + 128 * j + sw1);
                    short8 ahi, alo; unpackw(w0, w1, &ahi, &alo);
                    int kp = j * 32 + fk;
                    short8 b0 = *(const short8*)(Bp2 + kp);
                    short8 b1 = *(const short8*)(Bp2 + 512 + kp);
                    short8 b2 = *(const short8*)(Bp2 + 1024 + kp);
                    acc2 = MFMA(ahi, b0, acc2); acc2 = MFMA(alo, b1, acc2); acc2 = MFMA(ahi, b2, acc2);
                }
                union { unsigned long long q; float f[2]; } z0, z1;
                z0.q = zq0; z1.q = zq1;
                float zv[4] = {z0.f[0], z0.f[1], z1.f[0], z1.f[1]};
                float bhi = bh[c2];
#pragma unroll
                for (int jj = 0; jj < 4; ++jj) {
                    int lr   = fkc * 4 + jj;
                    int mrow = mt * 16 + lr;
                    unsigned int hw = *(const unsigned int*)((const char*)hbuf +
                        mt * 32768 + lr * 2048 + ((4 * c2) ^ ((lr & 7) << 4)));
                    float h   = b2f((unsigned short)(hw & 0xffffu)) +
                                b2f((unsigned short)(hw >> 16));
                    float pre = acc2[jj] + comb[slot][lr * 16 + fm] + bhi;
                    float e   = __expf(-2.f * pre);
                    float ht  = 2.f / (1.f + e) - 1.f;   // tanh
                    float hn  = zv[jj] * h + (1.f - zv[jj]) * ht;
                    out[(size_t)mrow * (T_ * NH) + (size_t)t * NH + c2] = hn;
                    if (t == T_ - 1)
                        out[(size_t)B_ * T_ * NH + mrow * NH + c2] = hn;
                    unsigned short hi = f2b(hn);
                    unsigned short lo = f2b(hn - b2f(hi));
                    ast32(HP + hp_idx(mrow, c2),
                          (unsigned int)hi | ((unsigned int)lo << 16));
                }
            }
        }
        __syncthreads();                    // drains stores
        if (tid == 0) ast32(flags + blk, ep + 2u);   // B2 arrive: own slot
    }
}

extern "C" void kernel_launch(void* const* d_in, const int* in_sizes, int n_in,
                              void* d_out, int out_size, void* d_ws, size_t ws_size,
                              hipStream_t stream) {
    (void)in_sizes; (void)n_in; (void)out_size; (void)ws_size;
    const float* X   = (const float*)d_in[0];
    const float* Wxz = (const float*)d_in[1];
    const float* Whz = (const float*)d_in[2];
    const float* bz  = (const float*)d_in[3];
    const float* Wxr = (const float*)d_in[4];
    const float* Whr = (const float*)d_in[5];
    const float* br  = (const float*)d_in[6];
    const float* Wxh = (const float*)d_in[7];
    const float* Whh = (const float*)d_in[8];
    const float* bh  = (const float*)d_in[9];
    float* out = (float*)d_out;

    char* ws = (char*)d_ws;
    unsigned int* flags = (unsigned int*)ws;                      // 256 B (64 slots)
    float* Zt         = (float*)(ws + 256);                       // 128 KB [c][m]
    unsigned int* HP  = (unsigned int*)(ws + 256 + 131072);       // 128 KB packed+swz
    unsigned int* RHP = (unsigned int*)(ws + 256 + 262144);       // 128 KB packed+swz
    unsigned short* Bzr = (unsigned short*)(ws + (1 << 20));      // 6.3 MB
    unsigned short* Bh  = Bzr + (size_t)1024 * KEFF;              // 3.2 MB

    // zero flags + H0 state each call (graph-replay safe)
    hipMemsetAsync(d_ws, 0, 1 << 20, stream);
    prepack<<<dim3(12, 1536), 256, 0, stream>>>(Wxz, Whz, Wxr, Whr, Wxh, Whh, Bzr, Bh);
    gru_seq<<<NBLK, NTHR, 0, stream>>>(X, bz, br, bh, out, Zt, HP, RHP, Bzr, Bh, flags);
}

// Round 6
// 14470.013 us; speedup vs baseline: 2.0510x; 1.0216x over previous
//
#include <hip/hip_runtime.h>

#define B_   64
#define T_   512
#define KIN  512
#define NH   512
#define KEFF 3072   // 6 segments x 512
#define NBLK 64
#define NTHR 512

typedef __attribute__((ext_vector_type(8))) short short8;
typedef __attribute__((ext_vector_type(4))) float f32x4;
typedef __attribute__((ext_vector_type(4))) unsigned int u32x4;

// bf16 round-to-nearest-even via bit ops
__device__ __forceinline__ unsigned short f2b(float f) {
    union { float f; unsigned int u; } v; v.f = f;
    unsigned int u = v.u;
    return (unsigned short)((u + 0x7FFFu + ((u >> 16) & 1u)) >> 16);
}
__device__ __forceinline__ float b2f(unsigned short h) {
    union { float f; unsigned int u; } v; v.u = ((unsigned int)h) << 16;
    return v.f;
}

// ---------------------------------------------------------------------------
// Prepack (proven): B' [n][keff] bf16. Segments:
//   seg0: Whi(H) seg1: Whi(H) seg2: Wlo(H) seg3: Whi(X) seg4: Whi(X) seg5: Wlo(X)
// ---------------------------------------------------------------------------
__global__ void prepack(const float* __restrict__ Wxz, const float* __restrict__ Whz,
                        const float* __restrict__ Wxr, const float* __restrict__ Whr,
                        const float* __restrict__ Wxh, const float* __restrict__ Whh,
                        unsigned short* __restrict__ Bzr, unsigned short* __restrict__ Bh) {
    int keff = blockIdx.x * 256 + threadIdx.x;  // 0..3071
    int n    = blockIdx.y;                      // 0..1535
    int seg  = keff >> 9;
    int k    = keff & 511;
    const float* src;
    int c;
    if (n < 512)       { c = n;        src = (seg < 3) ? Whz : Wxz; }
    else if (n < 1024) { c = n - 512;  src = (seg < 3) ? Whr : Wxr; }
    else               { c = n - 1024; src = (seg < 3) ? Whh : Wxh; }
    float w = src[k * NH + c];
    unsigned short hi = f2b(w);
    unsigned short o  = (seg == 2 || seg == 5) ? f2b(w - b2f(hi)) : hi;
    if (n < 1024) Bzr[(size_t)n * KEFF + keff] = o;
    else          Bh[(size_t)(n - 1024) * KEFF + keff] = o;
}

// Coherent ops (proven): relaxed+agent -> sc-bit loads/stores, no cache
// maintenance anywhere -> weights stay L2-warm all 512 steps.
__device__ __forceinline__ unsigned int ald32(const unsigned int* p) {
    return __hip_atomic_load(p, __ATOMIC_RELAXED, __HIP_MEMORY_SCOPE_AGENT);
}
__device__ __forceinline__ unsigned long long ald64(const void* p) {
    return __hip_atomic_load((const unsigned long long*)p, __ATOMIC_RELAXED,
                             __HIP_MEMORY_SCOPE_AGENT);
}
__device__ __forceinline__ void ast32(unsigned int* p, unsigned int v) {
    __hip_atomic_store(p, v, __ATOMIC_RELAXED, __HIP_MEMORY_SCOPE_AGENT);
}
__device__ __forceinline__ void ast64(void* p, unsigned long long v) {
    __hip_atomic_store((unsigned long long*)p, v, __ATOMIC_RELAXED,
                       __HIP_MEMORY_SCOPE_AGENT);
}

// Flag barrier (proven round 5): arrival = store own slot; wait = wave-0
// 64-lane coalesced poll of all 64 flags + __all vote.
__device__ __forceinline__ void flag_wait(const unsigned int* flags,
                                          unsigned int tgt, int lane) {
    while (1) {
        unsigned int v = ald32(flags + lane);
        if (__all((int)(v >= tgt))) break;
    }
    __builtin_amdgcn_sched_barrier(0);
}

// XOR-permuted global word index for HP/RHP (matches linear gload_lds +
// swizzled ds_read).
__device__ __forceinline__ int hp_idx(int m, int c) {
    return m * 512 + (c ^ ((m & 7) << 2));
}

// fp32 -> bf16 hi/lo split of 8 consecutive X elements
__device__ __forceinline__ void cvt_x8(const float* xr, int kp, short8* ahi, short8* alo) {
    f32x4 x0 = *(const f32x4*)(xr + kp);
    f32x4 x1 = *(const f32x4*)(xr + kp + 4);
#pragma unroll
    for (int i = 0; i < 4; ++i) {
        unsigned short h0 = f2b(x0[i]);
        (*ahi)[i] = (short)h0; (*alo)[i] = (short)f2b(x0[i] - b2f(h0));
        unsigned short h1 = f2b(x1[i]);
        (*ahi)[4 + i] = (short)h1; (*alo)[4 + i] = (short)f2b(x1[i] - b2f(h1));
    }
}

// 8 packed u32 (hi|lo<<16) -> hi/lo short8 fragments
__device__ __forceinline__ void unpackw(u32x4 w0, u32x4 w1, short8* ahi, short8* alo) {
    union { unsigned int u[4]; short8 v; } H, L;
    H.u[0] = __builtin_amdgcn_perm(w0[1], w0[0], 0x05040100u);
    H.u[1] = __builtin_amdgcn_perm(w0[3], w0[2], 0x05040100u);
    H.u[2] = __builtin_amdgcn_perm(w1[1], w1[0], 0x05040100u);
    H.u[3] = __builtin_amdgcn_perm(w1[3], w1[2], 0x05040100u);
    L.u[0] = __builtin_amdgcn_perm(w0[1], w0[0], 0x07060302u);
    L.u[1] = __builtin_amdgcn_perm(w0[3], w0[2], 0x07060302u);
    L.u[2] = __builtin_amdgcn_perm(w1[1], w1[0], 0x07060302u);
    L.u[3] = __builtin_amdgcn_perm(w1[3], w1[2], 0x07060302u);
    *ahi = H.v; *alo = L.v;
}

#define MFMA(a, b, c) __builtin_amdgcn_mfma_f32_16x16x32_bf16((a), (b), (c), 0, 0, 0)

// ---------------------------------------------------------------------------
// Persistent GRU, wave-specialized. 64 blocks x 512 threads (8 waves,
// 2/SIMD: each SIMD pairs one H-crew wave with one X-crew wave).
//   H-crew (waves 0-3): the sequential critical path — H-GEMM (P1),
//     RH-GEMM (P2, K-split over wave pairs), epilogues, coherent publishes.
//   X-crew (waves 4-7): computes step t+1's X@Wx preacts (3-term) into LDS
//     double buffers xp1/xp2 — entirely OFF the critical path.
// Comms skeleton (flags, epochs, HP/RHP/Zt via MALL) identical to round 5.
// ---------------------------------------------------------------------------
__global__ void __launch_bounds__(NTHR, 2) gru_seq(
    const float* __restrict__ X, const float* __restrict__ bz,
    const float* __restrict__ br, const float* __restrict__ bh,
    float* __restrict__ out, float* __restrict__ Zt,
    unsigned int* __restrict__ HP, unsigned int* __restrict__ RHP,
    const unsigned short* __restrict__ Bzr, const unsigned short* __restrict__ Bh,
    unsigned int* flags) {
    const int blk  = blockIdx.x;
    const int tid  = threadIdx.x;
    const int wv   = tid >> 6;          // 0..7
    const int hwv  = wv & 3;            // role-local wave id
    const bool xcrew = wv >= 4;
    const int lane = tid & 63;
    const int fm   = lane & 15;
    const int fkc  = lane >> 4;
    const int fk   = fkc * 8;

    __shared__ unsigned int hbuf[4 * 16 * 512];   // 128 KB H/RH staging
    __shared__ float xp1[2][4][16][16];           // 8 KB  P1 X-preacts (dbuf)
    __shared__ float xp2a[2][2][16][16];          // 4 KB  P2 X-preacts jh=0
    __shared__ float xp2b[2][2][16][16];          // 4 KB  P2 X-preacts jh=1
    __shared__ float comb[2][256];                // 2 KB  P2 H-part K-combine

    // phase-1 geometry: block owns zr-ntile blk, wave hwv owns mtile hwv
    const int m1 = hwv * 16 + fm;
    const unsigned short* Bp1 = Bzr + (size_t)(blk * 16 + fm) * KEFF;
    const int c1 = blk * 16 + fm;

    // phase-2 geometry: mt = blk&3; tasks s2i in {0,1} -> nt; jh = K-half
    const int mt  = blk & 3;
    const int s2i = hwv >> 1;
    const int jh  = hwv & 1;
    const int nt  = (blk >> 2) * 2 + s2i;
    const int m2  = mt * 16 + fm;
    const unsigned short* Bp2 = Bh + (size_t)(nt * 16 + fm) * KEFF;
    const int c2 = nt * 16 + fm;

    const int key = (fm & 7) << 4;
    const int sw0 = (32 * fkc) ^ key;
    const int sw1 = (32 * fkc + 16) ^ key;
    const char* HPb  = (const char*)HP;
    const char* RHPb = (const char*)RHP;

    const float bias1 = (blk < 32) ? bz[c1] : br[c1 - 512];
    const float bhi   = bh[c2];

    // X-crew producers ------------------------------------------------------
    auto xg1 = [&](int tt, int buf) {   // P1 X-preacts: mtile hwv, 16 zr-cols
        f32x4 acc = {0.f, 0.f, 0.f, 0.f};
        const float* xr = X + (size_t)m1 * (T_ * KIN) + (size_t)tt * KIN;
#pragma unroll 4
        for (int j = 0; j < 16; ++j) {
            int kp = j * 32 + fk;
            short8 xhi, xlo; cvt_x8(xr, kp, &xhi, &xlo);
            short8 b3 = *(const short8*)(Bp1 + 1536 + kp);
            short8 b4 = *(const short8*)(Bp1 + 2048 + kp);
            short8 b5 = *(const short8*)(Bp1 + 2560 + kp);
            acc = MFMA(xhi, b3, acc); acc = MFMA(xlo, b4, acc); acc = MFMA(xhi, b5, acc);
        }
#pragma unroll
        for (int jj = 0; jj < 4; ++jj) xp1[buf][hwv][fkc * 4 + jj][fm] = acc[jj];
    };
    auto xg2 = [&](int tt, int buf) {   // P2 X-preacts: (mt, nt(s2i)), K-half jh
        f32x4 acc = {0.f, 0.f, 0.f, 0.f};
        const float* xr = X + (size_t)m2 * (T_ * KIN) + (size_t)tt * KIN;
#pragma unroll
        for (int j = jh * 8; j < jh * 8 + 8; ++j) {
            int kp = j * 32 + fk;
            short8 xhi, xlo; cvt_x8(xr, kp, &xhi, &xlo);
            short8 b3 = *(const short8*)(Bp2 + 1536 + kp);
            short8 b4 = *(const short8*)(Bp2 + 2048 + kp);
            short8 b5 = *(const short8*)(Bp2 + 2560 + kp);
            acc = MFMA(xhi, b3, acc); acc = MFMA(xlo, b4, acc); acc = MFMA(xhi, b5, acc);
        }
        float (*dst)[16][16] = jh ? xp2b[buf] : xp2a[buf];
#pragma unroll
        for (int jj = 0; jj < 4; ++jj) dst[s2i][fkc * 4 + jj][fm] = acc[jj];
    };

    // prologue: X-preacts for t=0
    if (xcrew) { xg1(0, 0); xg2(0, 0); }
    __syncthreads();                                   // S0

    for (int t = 0; t < T_; ++t) {
        const int bufc = t & 1, bufn = bufc ^ 1;
        const unsigned int ep = (unsigned int)t * 2u;
        // ------------------------- phase 1: Z and R -------------------------
        if (wv == 0 && t) flag_wait(flags, ep, lane);  // H(t-1) published
        __syncthreads();                               // S1
        if (!xcrew) {
            // stage own 32 KB H slice -> LDS, coherent
            const char* src = HPb + hwv * 32768;
            char* dst = (char*)hbuf + hwv * 32768;
#pragma unroll
            for (int i = 0; i < 32; ++i)
                __builtin_amdgcn_global_load_lds(
                    (const unsigned int*)(src + i * 1024 + lane * 16),
                    (unsigned int*)(dst + i * 1024), 16, 0, 0x11);
            asm volatile("s_waitcnt vmcnt(0)" ::: "memory");
            __builtin_amdgcn_sched_barrier(0);
            // H-GEMM (segs 0..2) from LDS
            f32x4 acc = {0.f, 0.f, 0.f, 0.f};
            const char* sl = (const char*)hbuf + hwv * 32768 + fm * 2048;
#pragma unroll 4
            for (int j = 0; j < 16; ++j) {
                u32x4 w0 = *(const u32x4*)(sl + 128 * j + sw0);
                u32x4 w1 = *(const u32x4*)(sl + 128 * j + sw1);
                short8 ahi, alo; unpackw(w0, w1, &ahi, &alo);
                int kp = j * 32 + fk;
                short8 b0 = *(const short8*)(Bp1 + kp);
                short8 b1 = *(const short8*)(Bp1 + 512 + kp);
                short8 b2 = *(const short8*)(Bp1 + 1024 + kp);
                acc = MFMA(ahi, b0, acc); acc = MFMA(alo, b1, acc); acc = MFMA(ahi, b2, acc);
            }
            if (blk < 32) {             // z-gate -> Zt [c][m]
                float g[4];
#pragma unroll
                for (int jj = 0; jj < 4; ++jj)
                    g[jj] = 1.f / (1.f + __expf(-(acc[jj] +
                              xp1[bufc][hwv][fkc * 4 + jj][fm] + bias1)));
                union { float f[2]; unsigned long long q; } p0, p1;
                p0.f[0] = g[0]; p0.f[1] = g[1];
                p1.f[0] = g[2]; p1.f[1] = g[3];
                float* zp = Zt + c1 * 64 + hwv * 16 + fkc * 4;
                ast64(zp, p0.q); ast64(zp + 2, p1.q);
            } else {                    // r-gate -> RH packed (H from LDS)
                int cr = c1 - 512;
#pragma unroll
                for (int jj = 0; jj < 4; ++jj) {
                    int lr = fkc * 4 + jj;
                    unsigned int hw = *(const unsigned int*)((const char*)hbuf +
                        hwv * 32768 + lr * 2048 + ((4 * cr) ^ ((lr & 7) << 4)));
                    float h  = b2f((unsigned short)(hw & 0xffffu)) +
                               b2f((unsigned short)(hw >> 16));
                    float gr = 1.f / (1.f + __expf(-(acc[jj] +
                                 xp1[bufc][hwv][lr][fm] + bias1)));
                    float rh = gr * h;
                    unsigned short hi = f2b(rh);
                    unsigned short lo = f2b(rh - b2f(hi));
                    ast32(RHP + hp_idx(hwv * 16 + lr, cr),
                          (unsigned int)hi | ((unsigned int)lo << 16));
                }
            }
        } else if (t + 1 < T_) {
            xg1(t + 1, bufn);           // off-path: next step's P1 X-preacts
        }
        __syncthreads();                               // S2: drains stores
        if (tid == 0) ast32(flags + blk, ep + 1u);     // B1 arrive
        // ------------------------- phase 2: h~ and H update ------------------
        if (wv == 0) flag_wait(flags, ep + 1u, lane);  // all P1 done
        if (xcrew && t + 1 < T_) xg2(t + 1, bufn);     // overlaps the poll
        __syncthreads();                               // S3
        unsigned long long zq0 = 0, zq1 = 0;
        if (!xcrew) {
            if (jh == 0) {              // prefetch Z (hides MALL latency)
                const float* zp = Zt + c2 * 64 + mt * 16 + fkc * 4;
                zq0 = ald64(zp); zq1 = ald64(zp + 2);
            }
            // stage RH rows [16mt,16mt+16) -> slice (mt+2)&3
            const char* srcR = RHPb + mt * 32768;
            char* dstR = (char*)hbuf + ((mt + 2) & 3) * 32768;
#pragma unroll
            for (int i = 0; i < 8; ++i) {
                int o = (hwv * 8 + i) * 1024;
                __builtin_amdgcn_global_load_lds(
                    (const unsigned int*)(srcR + o + lane * 16),
                    (unsigned int*)(dstR + o), 16, 0, 0x11);
            }
            asm volatile("s_waitcnt vmcnt(0)" ::: "memory");
            __builtin_amdgcn_sched_barrier(0);
        }
        __syncthreads();                               // S3b: staged RH visible
        f32x4 acc2 = {0.f, 0.f, 0.f, 0.f};
        if (!xcrew) {
            // RH-GEMM (segs 0..2), K-half jh
            const char* sl2 = (const char*)hbuf + ((mt + 2) & 3) * 32768 + fm * 2048;
#pragma unroll
            for (int j = jh * 8; j < jh * 8 + 8; ++j) {
                u32x4 w0 = *(const u32x4*)(sl2 + 128 * j + sw0);
                u32x4 w1 = *(const u32x4*)(sl2 + 128 * j + sw1);
                short8 ahi, alo; unpackw(w0, w1, &ahi, &alo);
                int kp = j * 32 + fk;
                short8 b0 = *(const short8*)(Bp2 + kp);
                short8 b1 = *(const short8*)(Bp2 + 512 + kp);
                short8 b2 = *(const short8*)(Bp2 + 1024 + kp);
                acc2 = MFMA(ahi, b0, acc2); acc2 = MFMA(alo, b1, acc2); acc2 = MFMA(ahi, b2, acc2);
            }
            if (jh == 1) {
#pragma unroll
                for (int jj = 0; jj < 4; ++jj)
                    comb[s2i][(fkc * 4 + jj) * 16 + fm] = acc2[jj];
            }
        }
        __syncthreads();                               // S4a: comb ready
        if (!xcrew && jh == 0) {
            union { unsigned long long q; float f[2]; } z0, z1;
            z0.q = zq0; z1.q = zq1;
            float zv[4] = {z0.f[0], z0.f[1], z1.f[0], z1.f[1]};
#pragma unroll
            for (int jj = 0; jj < 4; ++jj) {
                int lr   = fkc * 4 + jj;
                int mrow = mt * 16 + lr;
                unsigned int hw = *(const unsigned int*)((const char*)hbuf +
                    mt * 32768 + lr * 2048 + ((4 * c2) ^ ((lr & 7) << 4)));
                float h   = b2f((unsigned short)(hw & 0xffffu)) +
                            b2f((unsigned short)(hw >> 16));
                float pre = acc2[jj] + comb[s2i][lr * 16 + fm] +
                            xp2a[bufc][s2i][lr][fm] + xp2b[bufc][s2i][lr][fm] + bhi;
                float e   = __expf(-2.f * pre);
                float ht  = 2.f / (1.f + e) - 1.f;     // tanh
                float hn  = zv[jj] * h + (1.f - zv[jj]) * ht;
                out[(size_t)mrow * (T_ * NH) + (size_t)t * NH + c2] = hn;
                if (t == T_ - 1)
                    out[(size_t)B_ * T_ * NH + mrow * NH + c2] = hn;
                unsigned short hi = f2b(hn);
                unsigned short lo = f2b(hn - b2f(hi));
                ast32(HP + hp_idx(mrow, c2),
                      (unsigned int)hi | ((unsigned int)lo << 16));
            }
        }
        __syncthreads();                               // S4: drains stores
        if (tid == 0) ast32(flags + blk, ep + 2u);     // B2 arrive
    }
}

extern "C" void kernel_launch(void* const* d_in, const int* in_sizes, int n_in,
                              void* d_out, int out_size, void* d_ws, size_t ws_size,
                              hipStream_t stream) {
    (void)in_sizes; (void)n_in; (void)out_size; (void)ws_size;
    const float* X   = (const float*)d_in[0];
    const float* Wxz = (const float*)d_in[1];
    const float* Whz = (const float*)d_in[2];
    const float* bz  = (const float*)d_in[3];
    const float* Wxr = (const float*)d_in[4];
    const float* Whr = (const float*)d_in[5];
    const float* br  = (const float*)d_in[6];
    const float* Wxh = (const float*)d_in[7];
    const float* Whh = (const float*)d_in[8];
    const float* bh  = (const float*)d_in[9];
    float* out = (float*)d_out;

    char* ws = (char*)d_ws;
    unsigned int* flags = (unsigned int*)ws;                      // 256 B (64 slots)
    float* Zt         = (float*)(ws + 256);                       // 128 KB [c][m]
    unsigned int* HP  = (unsigned int*)(ws + 256 + 131072);       // 128 KB packed+swz
    unsigned int* RHP = (unsigned int*)(ws + 256 + 262144);       // 128 KB packed+swz
    unsigned short* Bzr = (unsigned short*)(ws + (1 << 20));      // 6.3 MB
    unsigned short* Bh  = Bzr + (size_t)1024 * KEFF;              // 3.2 MB

    // zero flags + H0 state each call (graph-replay safe)
    hipMemsetAsync(d_ws, 0, 1 << 20, stream);
    prepack<<<dim3(12, 1536), 256, 0, stream>>>(Wxz, Whz, Wxr, Whr, Wxh, Whh, Bzr, Bh);
    gru_seq<<<NBLK, NTHR, 0, stream>>>(X, bz, br, bh, out, Zt, HP, RHP, Bzr, Bh, flags);
}